// Round 15
// baseline (129.099 us; speedup 1.0000x reference)
//
#include <hip/hip_runtime.h>
#include <stdint.h>

using ushort8 = __attribute__((ext_vector_type(8))) unsigned short;
using bf16x8  = __attribute__((ext_vector_type(8))) __bf16;
using f32x16  = __attribute__((ext_vector_type(16))) float;
using f32x2   = __attribute__((ext_vector_type(2))) float;
using u32x4   = __attribute__((ext_vector_type(4))) uint32_t;
using us4     = __attribute__((ext_vector_type(4))) unsigned short;

__device__ __forceinline__ unsigned short f2bf(float x){
  uint32_t u = __builtin_bit_cast(uint32_t, x);
  u = (u + 0x7FFFu + ((u >> 16) & 1u)) >> 16;   // RNE
  return (unsigned short)u;
}
__device__ __forceinline__ float bf2f(unsigned short b){
  uint32_t u = ((uint32_t)b) << 16;
  return __builtin_bit_cast(float, u);
}

__device__ __forceinline__ f32x16 mfma16(bf16x8 a, bf16x8 b, f32x16 c){
  return __builtin_amdgcn_mfma_f32_32x32x16_bf16(a, b, c, 0, 0, 0);
}

__device__ __forceinline__ bf16x8 cvt8(const float* p){
  ushort8 v;
  #pragma unroll
  for (int j = 0; j < 8; ++j) v[j] = f2bf(p[j]);
  return __builtin_bit_cast(bf16x8, v);
}

// Pre-pass (verbatim, verified): Wb4[s][slice(pt,ch)][granule q][8 bf16].
// Granule q = cc*64 + lg*32 + l31 holds A-frag chunk for lane (l31,lg), frag cc:
//   p = pt*32 + l31, c = ch*64 + cc*16 + lg*8 + j.
// s<128: A[p][c] = W[(s*128+p)*128+c]; s=128: A[p][i] = b[i*128+p].
__global__ void prep_wb4(const float* __restrict__ W, const float* __restrict__ bias,
                         unsigned short* __restrict__ Wb4){
  int e = blockIdx.x * 256 + threadIdx.x;
  if (e >= 129 * 16384) return;
  int jj = e & 7, q = (e >> 3) & 255, sl = (e >> 11) & 7, s = e >> 14;
  int ch = sl & 1, pt = sl >> 1;
  int cc = q >> 6, lg = (q >> 5) & 1, l31 = q & 31;
  int p = pt * 32 + l31;
  int c = ch * 64 + cc * 16 + lg * 8 + jj;
  float v = (s < 128) ? W[(s << 14) + (p << 7) + c] : bias[(c << 7) + p];
  Wb4[e] = f2bf(v);
}

// dynmlp: grid 256 = 128 token-tiles x 2 K-halves (tt=b>>1, h=b&1 -> XCD b&7
// serves one fixed h, 2.1MB L2 footprint). 512 thr = 8 waves = 4 pt x 2 ch;
// wave tile 32p x 128t (F=4) x 64c. A-fragments global->register, DEPTH-3
// pipeline (banks b0..b2, statically indexed), cover = 2 step-bodies.
// PER-WAVE STEP ROTATION (ps = (k + wv*8)&63): decorrelates wave stalls and
// spreads the XCD read set over all 64 step images (K-sum order-invariant).
// __launch_bounds__(512,1): 256-VGPR budget (r7 spilled at the 128 cap).
// LDS: imgT 16KB (union with 66KB ldsY used only in epilogue).
// ROUND-8 CHAMPION SOURCE, byte-for-byte (94.78us total, dynmlp 80.2us,
// FETCH 24.5MB WRITE 16.4MB, zero spill). Both "safe trims" (r13 rot-spread,
// r14 bf16 epilogue) tripped the 128-VGPR regalloc cliff -> scratch spill.
__global__ __launch_bounds__(512, 1)
void dynmlp(const float* __restrict__ img, const float* __restrict__ loc,
            const unsigned short* __restrict__ Wb4, float* __restrict__ part){
  __shared__ __align__(16) char smem[66048];
  unsigned short* imgT = (unsigned short*)smem;   // [64 s][slot(t)] u16, 16KB
  float* ldsY = (float*)smem;                     // [128 t][129 p] f32 (epilogue)

  const int b = blockIdx.x;
  const int tt = b >> 1, h = b & 1;
  const int tid = threadIdx.x, lane = tid & 63, wv = tid >> 6;
  const int pt = wv >> 1, ch = wv & 1;
  const int l31 = lane & 31, lg = lane >> 5;
  const int t0 = tt * 128;
  const int rot = wv << 3;                        // per-wave step rotation

  const char* wlane = (const char*)Wb4 +
      ((size_t)(h * 64) * 8 + (size_t)(pt * 2 + ch)) * 4096 + (lane << 4);
  const char* blane = (const char*)Wb4 +
      ((size_t)128 * 8 + (size_t)(pt * 2 + ch)) * 4096 + (lane << 4);

  // ---- imgT fill: slot(t) = (t&31)*4 + (t>>5); row s = i - h*64 ----
  for (int e = tid; e < 2048; e += 512){
    int tl = e & 127, iq = e >> 7;
    float4 v = *(const float4*)&img[(size_t)(t0 + tl) * 128 + h * 64 + iq * 4];
    int slot = (tl & 31) * 4 + (tl >> 5);
    imgT[(iq * 4 + 0) * 128 + slot] = f2bf(v.x);
    imgT[(iq * 4 + 1) * 128 + slot] = f2bf(v.y);
    imgT[(iq * 4 + 2) * 128 + slot] = f2bf(v.z);
    imgT[(iq * 4 + 3) * 128 + slot] = f2bf(v.w);
  }

  // ---- register-stationary B-frags (loc, this wave's c-half) ----
  bf16x8 bfr[4][4];
  #pragma unroll
  for (int f = 0; f < 4; ++f){
    int t = t0 + f * 32 + l31;
    #pragma unroll
    for (int cc = 0; cc < 4; ++cc)
      bfr[f][cc] = cvt8(&loc[(size_t)t * 128 + ch * 64 + cc * 16 + lg * 8]);
  }

  // persistent zero C-operand (asm-pinned so it is materialized ONCE)
  f32x16 Z;
  #pragma unroll
  for (int i = 0; i < 16; ++i) Z[i] = 0.0f;
  asm volatile("" : "+v"(Z));

  f32x16 acc[4];
  #pragma unroll
  for (int f = 0; f < 4; ++f) acc[f] = Z;

  #define LP(K) (((K) + rot) & 63)
  #define LOADB(BK, STEP) do { \
    const u32x4* _g = (const u32x4*)(wlane + (size_t)LP(STEP) * 32768); \
    BK[0] = _g[0]; BK[1] = _g[64]; BK[2] = _g[128]; BK[3] = _g[192]; \
  } while (0)

  // ---- depth-3 prologue ----
  u32x4 b0[4], b1[4], b2[4];
  LOADB(b0, 0); LOADB(b1, 1); LOADB(b2, 2);

  __syncthreads();                     // imgT ready

  const unsigned short* imgP = imgT + l31 * 4;

  // body: two MFMA clusters of 2 chains; plain C++ scaled accumulate (packed FMA)
  #define STEPBODY(AV, W4) do { \
    bf16x8 a0 = __builtin_bit_cast(bf16x8, AV[0]); \
    bf16x8 a1 = __builtin_bit_cast(bf16x8, AV[1]); \
    bf16x8 a2 = __builtin_bit_cast(bf16x8, AV[2]); \
    bf16x8 a3 = __builtin_bit_cast(bf16x8, AV[3]); \
    float s0 = bf2f(W4[0]), s1 = bf2f(W4[1]), s2 = bf2f(W4[2]), s3 = bf2f(W4[3]); \
    __builtin_amdgcn_s_setprio(1); \
    f32x16 T0 = mfma16(a0, bfr[0][0], Z); \
    f32x16 T1 = mfma16(a0, bfr[1][0], Z); \
    T0 = mfma16(a1, bfr[0][1], T0); T1 = mfma16(a1, bfr[1][1], T1); \
    T0 = mfma16(a2, bfr[0][2], T0); T1 = mfma16(a2, bfr[1][2], T1); \
    T0 = mfma16(a3, bfr[0][3], T0); T1 = mfma16(a3, bfr[1][3], T1); \
    __builtin_amdgcn_s_setprio(0); \
    acc[0] += T0 * s0; acc[1] += T1 * s1; \
    __builtin_amdgcn_s_setprio(1); \
    f32x16 U0 = mfma16(a0, bfr[2][0], Z); \
    f32x16 U1 = mfma16(a0, bfr[3][0], Z); \
    U0 = mfma16(a1, bfr[2][1], U0); U1 = mfma16(a1, bfr[3][1], U1); \
    U0 = mfma16(a2, bfr[2][2], U0); U1 = mfma16(a2, bfr[3][2], U1); \
    U0 = mfma16(a3, bfr[2][3], U0); U1 = mfma16(a3, bfr[3][3], U1); \
    __builtin_amdgcn_s_setprio(0); \
    acc[2] += U0 * s2; acc[3] += U1 * s3; \
  } while (0)

  // ---- main loop: k = 0,3,...,57: bodies k..k+2, loads k+3..k+5 ----
  for (int k = 0; k < 60; k += 3){
    us4 w;
    w = *(const us4*)(imgP + LP(k + 0) * 128); STEPBODY(b0, w); LOADB(b0, k + 3);
    w = *(const us4*)(imgP + LP(k + 1) * 128); STEPBODY(b1, w); LOADB(b1, k + 4);
    w = *(const us4*)(imgP + LP(k + 2) * 128); STEPBODY(b2, w); LOADB(b2, k + 5);
  }
  // ---- tail: bodies 60..63 (banks hold 60,61,62); bias prefetch into b1 ----
  {
    us4 w;
    w = *(const us4*)(imgP + LP(60) * 128); STEPBODY(b0, w); LOADB(b0, 63);
    w = *(const us4*)(imgP + LP(61) * 128); STEPBODY(b1, w);
    if (h == 0){
      const u32x4* _g = (const u32x4*)blane;
      b1[0] = _g[0]; b1[1] = _g[64]; b1[2] = _g[128]; b1[3] = _g[192];
    }
    w = *(const us4*)(imgP + LP(62) * 128); STEPBODY(b2, w);
    w = *(const us4*)(imgP + LP(63) * 128); STEPBODY(b0, w);
  }

  // ---- bias step (h==0): acc += A_bias x img-frags (no scale) ----
  if (h == 0){
    bf16x8 a0 = __builtin_bit_cast(bf16x8, b1[0]);
    bf16x8 a1 = __builtin_bit_cast(bf16x8, b1[1]);
    bf16x8 a2 = __builtin_bit_cast(bf16x8, b1[2]);
    bf16x8 a3 = __builtin_bit_cast(bf16x8, b1[3]);
    #pragma unroll
    for (int f = 0; f < 4; ++f){
      size_t tr = (size_t)(t0 + f * 32 + l31) * 128 + ch * 64 + lg * 8;
      f32x16 T = mfma16(a0, cvt8(&img[tr]),      Z);
      T = mfma16(a1, cvt8(&img[tr + 16]), T);
      T = mfma16(a2, cvt8(&img[tr + 32]), T);
      T = mfma16(a3, cvt8(&img[tr + 48]), T);
      acc[f] += T;
    }
  }

  // ---- epilogue: combine c-halves in LDS, write partial coalesced ----
  // C/D layout: col = l31 (t), row r = (r&3) + 8*(r>>2) + 4*lg (p)
  __syncthreads();   // imgT dead; ldsY takes over
  if (ch == 0){
    #pragma unroll
    for (int f = 0; f < 4; ++f){
      int t_l = f * 32 + l31;
      #pragma unroll
      for (int r = 0; r < 16; ++r){
        int p = pt * 32 + (r & 3) + 8 * (r >> 2) + 4 * lg;
        ldsY[t_l * 129 + p] = acc[f][r];
      }
    }
  }
  __syncthreads();
  if (ch == 1){
    #pragma unroll
    for (int f = 0; f < 4; ++f){
      int t_l = f * 32 + l31;
      #pragma unroll
      for (int r = 0; r < 16; ++r){
        int p = pt * 32 + (r & 3) + 8 * (r >> 2) + 4 * lg;
        ldsY[t_l * 129 + p] += acc[f][r];
      }
    }
  }
  __syncthreads();
  float* dst = part + ((size_t)h * 16384 + t0) * 128;
  #pragma unroll
  for (int k = 0; k < 8; ++k){
    int idx4 = k * 512 + tid;
    int t_l = idx4 >> 5, q = idx4 & 31;
    const float* s = &ldsY[t_l * 129 + q * 4];
    float4 v = {s[0], s[1], s[2], s[3]};
    *(float4*)&dst[t_l * 128 + q * 4] = v;
  }
}

// LN kernel: y = part0 + part1, LayerNorm + ReLU. grid 256 x 512 thr.
__global__ __launch_bounds__(512)
void lnk(const float* __restrict__ part, const float* __restrict__ gamma,
         const float* __restrict__ beta, float* __restrict__ out){
  const int tid = threadIdx.x, lane = tid & 63, wv = tid >> 6;
  const float* p0 = part;
  const float* p1 = part + (size_t)16384 * 128;
  float g0  = gamma[lane], g1 = gamma[lane + 64];
  float be0 = beta[lane],  be1 = beta[lane + 64];
  int tb = blockIdx.x * 64 + wv * 8;
  #pragma unroll 1
  for (int k = 0; k < 8; ++k){
    size_t t = tb + k;
    float y0 = p0[t * 128 + lane]      + p1[t * 128 + lane];
    float y1 = p0[t * 128 + 64 + lane] + p1[t * 128 + 64 + lane];
    float s = y0 + y1, sq = y0 * y0 + y1 * y1;
    #pragma unroll
    for (int m = 32; m >= 1; m >>= 1){
      s  += __shfl_xor(s, m, 64);
      sq += __shfl_xor(sq, m, 64);
    }
    float mean = s * (1.0f / 128.0f);
    float var  = sq * (1.0f / 128.0f) - mean * mean;
    float rs   = rsqrtf(var + 1e-5f);
    float o0 = fmaxf((y0 - mean) * rs * g0 + be0, 0.0f);
    float o1 = fmaxf((y1 - mean) * rs * g1 + be1, 0.0f);
    out[t * 128 + lane]      = o0;
    out[t * 128 + 64 + lane] = o1;
  }
}

extern "C" void kernel_launch(void* const* d_in, const int* in_sizes, int n_in,
                              void* d_out, int out_size, void* d_ws, size_t ws_size,
                              hipStream_t stream){
  const float* img   = (const float*)d_in[0];
  const float* loc   = (const float*)d_in[1];
  const float* W     = (const float*)d_in[2];
  const float* bias  = (const float*)d_in[3];
  const float* gamma = (const float*)d_in[4];
  const float* beta  = (const float*)d_in[5];
  float* out = (float*)d_out;
  unsigned short* Wb4 = (unsigned short*)d_ws;                 // 4,227,072 B
  float* part = (float*)((char*)d_ws + 4227072);               // 2 x 16384 x 128 f32

  prep_wb4<<<8256, 256, 0, stream>>>(W, bias, Wb4);
  dynmlp<<<256, 512, 0, stream>>>(img, loc, Wb4, part);
  lnk<<<256, 512, 0, stream>>>(part, gamma, beta, out);
}

// Round 16
// 94.596 us; speedup vs baseline: 1.3647x; 1.3647x over previous
//
#include <hip/hip_runtime.h>
#include <stdint.h>

using ushort8 = __attribute__((ext_vector_type(8))) unsigned short;
using bf16x8  = __attribute__((ext_vector_type(8))) __bf16;
using f32x16  = __attribute__((ext_vector_type(16))) float;
using f32x2   = __attribute__((ext_vector_type(2))) float;
using u32x4   = __attribute__((ext_vector_type(4))) uint32_t;
using us4     = __attribute__((ext_vector_type(4))) unsigned short;

__device__ __forceinline__ unsigned short f2bf(float x){
  uint32_t u = __builtin_bit_cast(uint32_t, x);
  u = (u + 0x7FFFu + ((u >> 16) & 1u)) >> 16;   // RNE
  return (unsigned short)u;
}
__device__ __forceinline__ float bf2f(unsigned short b){
  uint32_t u = ((uint32_t)b) << 16;
  return __builtin_bit_cast(float, u);
}

__device__ __forceinline__ f32x16 mfma16(bf16x8 a, bf16x8 b, f32x16 c){
  return __builtin_amdgcn_mfma_f32_32x32x16_bf16(a, b, c, 0, 0, 0);
}

__device__ __forceinline__ bf16x8 cvt8(const float* p){
  ushort8 v;
  #pragma unroll
  for (int j = 0; j < 8; ++j) v[j] = f2bf(p[j]);
  return __builtin_bit_cast(bf16x8, v);
}

// Pre-pass (unchanged, verified): Wb4[s][slice(pt,ch)][granule q][8 bf16].
// Granule q = cc*64 + lg*32 + l31 holds A-frag chunk for lane (l31,lg), frag cc:
//   p = pt*32 + l31, c = ch*64 + cc*16 + lg*8 + j.
// s<128: A[p][c] = W[(s*128+p)*128+c]; s=128: A[p][i] = b[i*128+p].
__global__ void prep_wb4(const float* __restrict__ W, const float* __restrict__ bias,
                         unsigned short* __restrict__ Wb4){
  int e = blockIdx.x * 256 + threadIdx.x;
  if (e >= 129 * 16384) return;
  int jj = e & 7, q = (e >> 3) & 255, sl = (e >> 11) & 7, s = e >> 14;
  int ch = sl & 1, pt = sl >> 1;
  int cc = q >> 6, lg = (q >> 5) & 1, l31 = q & 31;
  int p = pt * 32 + l31;
  int c = ch * 64 + cc * 16 + lg * 8 + jj;
  float v = (s < 128) ? W[(s << 14) + (p << 7) + c] : bias[(c << 7) + p];
  Wb4[e] = f2bf(v);
}

// dynmlp: grid 256 = 128 token-tiles x 2 K-halves (tt=b>>1, h=b&1 -> XCD b&7
// serves one fixed h, 2.1MB L2 footprint). 512 thr = 8 waves = 4 pt x 2 ch;
// wave tile 32p x 128t (F=4) x 64c. A-fragments global->register, DEPTH-3
// pipeline (banks b0..b2, statically indexed), cover = 2 step-bodies.
// PER-WAVE STEP ROTATION (ps = (k + wv*8)&63): decorrelates wave stalls and
// spreads the XCD read set over all 64 step images (K-sum order-invariant).
// __launch_bounds__(512,1): 256-VGPR budget (r7 spilled at the 128 cap).
// LDS: imgT 16KB (union with 66KB ldsY used only in epilogue).
// TRUE ROUND-8 CHAMPION (94.78us total, dynmlp 80.2us, VGPR 128, zero spill).
// Critical: accumulator is f32x2 accp[4][8] updated via in-place inline-asm
// v_pk_fma_f32 ("+v") -- the plain-C++ f32x16 acc[]+= form spills (r9/r10/r15).
__global__ __launch_bounds__(512, 1)
void dynmlp(const float* __restrict__ img, const float* __restrict__ loc,
            const unsigned short* __restrict__ Wb4, float* __restrict__ part){
  __shared__ __align__(16) char smem[66048];
  unsigned short* imgT = (unsigned short*)smem;   // [64 s][slot(t)] u16, 16KB
  float* ldsY = (float*)smem;                     // [128 t][129 p] f32 (epilogue)

  const int b = blockIdx.x;
  const int tt = b >> 1, h = b & 1;
  const int tid = threadIdx.x, lane = tid & 63, wv = tid >> 6;
  const int pt = wv >> 1, ch = wv & 1;
  const int l31 = lane & 31, lg = lane >> 5;
  const int t0 = tt * 128;
  const int rot = wv << 3;                        // per-wave step rotation

  const char* wlane = (const char*)Wb4 +
      ((size_t)(h * 64) * 8 + (size_t)(pt * 2 + ch)) * 4096 + (lane << 4);
  const char* blane = (const char*)Wb4 +
      ((size_t)128 * 8 + (size_t)(pt * 2 + ch)) * 4096 + (lane << 4);

  // ---- imgT fill: slot(t) = (t&31)*4 + (t>>5); row s = i - h*64 ----
  for (int e = tid; e < 2048; e += 512){
    int tl = e & 127, iq = e >> 7;
    float4 v = *(const float4*)&img[(size_t)(t0 + tl) * 128 + h * 64 + iq * 4];
    int slot = (tl & 31) * 4 + (tl >> 5);
    imgT[(iq * 4 + 0) * 128 + slot] = f2bf(v.x);
    imgT[(iq * 4 + 1) * 128 + slot] = f2bf(v.y);
    imgT[(iq * 4 + 2) * 128 + slot] = f2bf(v.z);
    imgT[(iq * 4 + 3) * 128 + slot] = f2bf(v.w);
  }

  // ---- register-stationary B-frags (loc, this wave's c-half) ----
  bf16x8 bfr[4][4];
  #pragma unroll
  for (int f = 0; f < 4; ++f){
    int t = t0 + f * 32 + l31;
    #pragma unroll
    for (int cc = 0; cc < 4; ++cc)
      bfr[f][cc] = cvt8(&loc[(size_t)t * 128 + ch * 64 + cc * 16 + lg * 8]);
  }

  // persistent zero C-operand (asm-pinned so it is materialized ONCE)
  f32x16 Z;
  #pragma unroll
  for (int i = 0; i < 16; ++i) Z[i] = 0.0f;
  asm volatile("" : "+v"(Z));

  // acc as 4 x 8 f32-pairs (pk_fma targets)
  f32x2 accp[4][8];
  #pragma unroll
  for (int f = 0; f < 4; ++f)
    #pragma unroll
    for (int q = 0; q < 8; ++q) accp[f][q] = (f32x2){0.0f, 0.0f};

  #define LP(K) (((K) + rot) & 63)
  #define LOADB(BK, STEP) do { \
    const u32x4* _g = (const u32x4*)(wlane + (size_t)LP(STEP) * 32768); \
    BK[0] = _g[0]; BK[1] = _g[64]; BK[2] = _g[128]; BK[3] = _g[192]; \
  } while (0)

  // ---- depth-3 prologue ----
  u32x4 b0[4], b1[4], b2[4];
  LOADB(b0, 0); LOADB(b1, 1); LOADB(b2, 2);

  __syncthreads();                     // imgT ready

  const unsigned short* imgP = imgT + l31 * 4;

  #define TAIL(T, S, F) do { \
    f32x2 _vs = {S, S}; \
    _Pragma("unroll") \
    for (int q = 0; q < 8; ++q){ \
      f32x2 _pp = {T[2*q], T[2*q+1]}; \
      asm("v_pk_fma_f32 %0, %1, %2, %0" : "+v"(accp[F][q]) : "v"(_pp), "v"(_vs)); \
    } \
  } while (0)

  // body: two MFMA clusters of 2 chains each (halves transient T pressure)
  #define STEPBODY(AV, W4) do { \
    bf16x8 a0 = __builtin_bit_cast(bf16x8, AV[0]); \
    bf16x8 a1 = __builtin_bit_cast(bf16x8, AV[1]); \
    bf16x8 a2 = __builtin_bit_cast(bf16x8, AV[2]); \
    bf16x8 a3 = __builtin_bit_cast(bf16x8, AV[3]); \
    float s0 = bf2f(W4[0]), s1 = bf2f(W4[1]), s2 = bf2f(W4[2]), s3 = bf2f(W4[3]); \
    __builtin_amdgcn_s_setprio(1); \
    f32x16 T0 = mfma16(a0, bfr[0][0], Z); \
    f32x16 T1 = mfma16(a0, bfr[1][0], Z); \
    T0 = mfma16(a1, bfr[0][1], T0); T1 = mfma16(a1, bfr[1][1], T1); \
    T0 = mfma16(a2, bfr[0][2], T0); T1 = mfma16(a2, bfr[1][2], T1); \
    T0 = mfma16(a3, bfr[0][3], T0); T1 = mfma16(a3, bfr[1][3], T1); \
    __builtin_amdgcn_s_setprio(0); \
    TAIL(T0, s0, 0); TAIL(T1, s1, 1); \
    __builtin_amdgcn_s_setprio(1); \
    f32x16 U0 = mfma16(a0, bfr[2][0], Z); \
    f32x16 U1 = mfma16(a0, bfr[3][0], Z); \
    U0 = mfma16(a1, bfr[2][1], U0); U1 = mfma16(a1, bfr[3][1], U1); \
    U0 = mfma16(a2, bfr[2][2], U0); U1 = mfma16(a2, bfr[3][2], U1); \
    U0 = mfma16(a3, bfr[2][3], U0); U1 = mfma16(a3, bfr[3][3], U1); \
    __builtin_amdgcn_s_setprio(0); \
    TAIL(U0, s2, 2); TAIL(U1, s3, 3); \
  } while (0)

  // ---- main loop: k = 0,3,...,57: bodies k..k+2, loads k+3..k+5 ----
  for (int k = 0; k < 60; k += 3){
    us4 w;
    w = *(const us4*)(imgP + LP(k + 0) * 128); STEPBODY(b0, w); LOADB(b0, k + 3);
    w = *(const us4*)(imgP + LP(k + 1) * 128); STEPBODY(b1, w); LOADB(b1, k + 4);
    w = *(const us4*)(imgP + LP(k + 2) * 128); STEPBODY(b2, w); LOADB(b2, k + 5);
  }
  // ---- tail: bodies 60..63 (banks hold 60,61,62); bias prefetch into b1 ----
  {
    us4 w;
    w = *(const us4*)(imgP + LP(60) * 128); STEPBODY(b0, w); LOADB(b0, 63);
    w = *(const us4*)(imgP + LP(61) * 128); STEPBODY(b1, w);
    if (h == 0){
      const u32x4* _g = (const u32x4*)blane;
      b1[0] = _g[0]; b1[1] = _g[64]; b1[2] = _g[128]; b1[3] = _g[192];
    }
    w = *(const us4*)(imgP + LP(62) * 128); STEPBODY(b2, w);
    w = *(const us4*)(imgP + LP(63) * 128); STEPBODY(b0, w);
  }

  // ---- bias step (h==0): acc += A_bias x img-frags (no scale) ----
  if (h == 0){
    bf16x8 a0 = __builtin_bit_cast(bf16x8, b1[0]);
    bf16x8 a1 = __builtin_bit_cast(bf16x8, b1[1]);
    bf16x8 a2 = __builtin_bit_cast(bf16x8, b1[2]);
    bf16x8 a3 = __builtin_bit_cast(bf16x8, b1[3]);
    #pragma unroll
    for (int f = 0; f < 4; ++f){
      size_t tr = (size_t)(t0 + f * 32 + l31) * 128 + ch * 64 + lg * 8;
      f32x16 T = mfma16(a0, cvt8(&img[tr]),      Z);
      T = mfma16(a1, cvt8(&img[tr + 16]), T);
      T = mfma16(a2, cvt8(&img[tr + 32]), T);
      T = mfma16(a3, cvt8(&img[tr + 48]), T);
      #pragma unroll
      for (int q = 0; q < 8; ++q){
        accp[f][q][0] += T[2*q];
        accp[f][q][1] += T[2*q+1];
      }
    }
  }

  // ---- epilogue: combine c-halves in LDS, write partial coalesced ----
  // C/D layout: col = l31 (t), row r = (r&3) + 8*(r>>2) + 4*lg (p)
  __syncthreads();   // imgT dead; ldsY takes over
  if (ch == 0){
    #pragma unroll
    for (int f = 0; f < 4; ++f){
      int t_l = f * 32 + l31;
      #pragma unroll
      for (int r = 0; r < 16; ++r){
        int p = pt * 32 + (r & 3) + 8 * (r >> 2) + 4 * lg;
        ldsY[t_l * 129 + p] = accp[f][r >> 1][r & 1];
      }
    }
  }
  __syncthreads();
  if (ch == 1){
    #pragma unroll
    for (int f = 0; f < 4; ++f){
      int t_l = f * 32 + l31;
      #pragma unroll
      for (int r = 0; r < 16; ++r){
        int p = pt * 32 + (r & 3) + 8 * (r >> 2) + 4 * lg;
        ldsY[t_l * 129 + p] += accp[f][r >> 1][r & 1];
      }
    }
  }
  __syncthreads();
  float* dst = part + ((size_t)h * 16384 + t0) * 128;
  #pragma unroll
  for (int k = 0; k < 8; ++k){
    int idx4 = k * 512 + tid;
    int t_l = idx4 >> 5, q = idx4 & 31;
    const float* s = &ldsY[t_l * 129 + q * 4];
    float4 v = {s[0], s[1], s[2], s[3]};
    *(float4*)&dst[t_l * 128 + q * 4] = v;
  }
}

// LN kernel: y = part0 + part1, LayerNorm + ReLU. grid 256 x 512 thr.
__global__ __launch_bounds__(512)
void lnk(const float* __restrict__ part, const float* __restrict__ gamma,
         const float* __restrict__ beta, float* __restrict__ out){
  const int tid = threadIdx.x, lane = tid & 63, wv = tid >> 6;
  const float* p0 = part;
  const float* p1 = part + (size_t)16384 * 128;
  float g0  = gamma[lane], g1 = gamma[lane + 64];
  float be0 = beta[lane],  be1 = beta[lane + 64];
  int tb = blockIdx.x * 64 + wv * 8;
  #pragma unroll 1
  for (int k = 0; k < 8; ++k){
    size_t t = tb + k;
    float y0 = p0[t * 128 + lane]      + p1[t * 128 + lane];
    float y1 = p0[t * 128 + 64 + lane] + p1[t * 128 + 64 + lane];
    float s = y0 + y1, sq = y0 * y0 + y1 * y1;
    #pragma unroll
    for (int m = 32; m >= 1; m >>= 1){
      s  += __shfl_xor(s, m, 64);
      sq += __shfl_xor(sq, m, 64);
    }
    float mean = s * (1.0f / 128.0f);
    float var  = sq * (1.0f / 128.0f) - mean * mean;
    float rs   = rsqrtf(var + 1e-5f);
    float o0 = fmaxf((y0 - mean) * rs * g0 + be0, 0.0f);
    float o1 = fmaxf((y1 - mean) * rs * g1 + be1, 0.0f);
    out[t * 128 + lane]      = o0;
    out[t * 128 + 64 + lane] = o1;
  }
}

extern "C" void kernel_launch(void* const* d_in, const int* in_sizes, int n_in,
                              void* d_out, int out_size, void* d_ws, size_t ws_size,
                              hipStream_t stream){
  const float* img   = (const float*)d_in[0];
  const float* loc   = (const float*)d_in[1];
  const float* W     = (const float*)d_in[2];
  const float* bias  = (const float*)d_in[3];
  const float* gamma = (const float*)d_in[4];
  const float* beta  = (const float*)d_in[5];
  float* out = (float*)d_out;
  unsigned short* Wb4 = (unsigned short*)d_ws;                 // 4,227,072 B
  float* part = (float*)((char*)d_ws + 4227072);               // 2 x 16384 x 128 f32

  prep_wb4<<<8256, 256, 0, stream>>>(W, bias, Wb4);
  dynmlp<<<256, 512, 0, stream>>>(img, loc, Wb4, part);
  lnk<<<256, 512, 0, stream>>>(part, gamma, beta, out);
}